// Round 20
// baseline (390.591 us; speedup 1.0000x reference)
//
#include <hip/hip_runtime.h>

// DGODE — round 21 (resubmit; round-19 bench failed on GPU acquisition).
//   r20 one-wave design with the LDS weight-staging FIX.
//   r20 failed NaN: staging loops wrote only the even 8-u16 chunk of each
//   16-u16 segment (seg stride counted 16 u16 but bf16x8v stores 8 u16) ->
//   half of w1l/w2l uninitialized -> GEMM1 consumed LDS garbage.
//   Fix: W1 row = 32 chunks of 8 u16 (idx<128*32, seg=(idx&31)*8);
//        W2 row = 16 chunks of 8 u16 (idx<128*16, seg=(idx&15)*8).
//   Design unchanged: one WAVE per tile, zero intra-stage barriers
//   (in-wave lgkmcnt orders LDS; own vmcnt(0) before inbox adds; lane-0
//   poll reconverges the wave), padded mailboxes, single-write snapshots.
// Same MFMA sequence per (m,n,k), same fp32 expression order => bit-identical
// output (absmax 0.015625).

typedef unsigned short u16;
typedef unsigned long long u64;
typedef __attribute__((ext_vector_type(8))) short bf16x8v;
typedef __attribute__((ext_vector_type(4))) float f32x4;

#define MFMA16(a, b, c) __builtin_amdgcn_mfma_f32_16x16x32_bf16(a, b, c, 0, 0, 0)

#define BN 4096
#define HN 128
#define DIN 1856
#define TILEW 320
#define IBSTRIDE 32   // inbox counter stride in ints (128B) — one LLC line each

__device__ __forceinline__ float bf2f(u16 u) {
  union { unsigned u; float f; } v; v.u = ((unsigned)u) << 16; return v.f;
}
__device__ __forceinline__ u16 f2bf(float f) {
  union { float f; unsigned u; } v; v.f = f;
  unsigned u = v.u;
  return (u16)((u + 0x7fffu + ((u >> 16) & 1u)) >> 16);  // RNE
}
__device__ __forceinline__ float ldx(const void* p, long idx, int isf) {
  return isf ? ((const float*)p)[idx] : bf2f(((const u16*)p)[idx]);
}
__device__ __forceinline__ int ldspk(const void* spk, int j, int i64) {
  return i64 ? ((const int*)spk)[2 * j] : ((const int*)spk)[j];
}

// coherent (LLC-point) 8B store, no cache maintenance (producer publish path)
__device__ __forceinline__ void cstore8(u16* p, u64 v) {
  __hip_atomic_store((u64*)p, v, __ATOMIC_RELAXED, __HIP_MEMORY_SCOPE_AGENT);
}

// ---------- per-array dtype detection (parallel) + inbox zeroing ----------
__global__ __launch_bounds__(256) void detect(
    const void* a0, const void* a1, const void* a2, const void* a3,
    const void* a4, const void* a5, const void* a6, const void* a7,
    const unsigned* spk_raw, int* flags, int* inbox) {
  __shared__ int part[256];
  const int b = blockIdx.x, t = threadIdx.x;
  int cnt = 0;
  if (b < 8) {
    const void* arr[8] = {a0, a1, a2, a3, a4, a5, a6, a7};
    const int nel[8] = {BN * DIN, BN * 3, DIN * HN, HN, 2 * HN * HN, HN, HN * HN, HN};
    const u16* p = (const u16*)arr[b];
    int ns = nel[b] / 2; if (ns > 512) ns = 512;
    for (int e = t; e < ns; e += 256) {
      unsigned ex = (p[2 * e] >> 7) & 0xFFu;
      if (ex < 64u) cnt++;
    }
  } else if (b == 8) {
    for (int e = t; e < 512; e += 256)
      if (spk_raw[2 * e + 1] != 0u) cnt++;
  } else {
    inbox[t * IBSTRIDE] = 0;   // b == 9: zero 256 padded inbox counters
    return;
  }
  part[t] = cnt;
  __syncthreads();
  #pragma unroll
  for (int o = 128; o > 0; o >>= 1) {
    if (t < o) part[t] += part[t + o];
    __syncthreads();
  }
  if (t == 0) {
    if (b < 8) flags[b] = (part[0] >= 2) ? 1 : 0;   // 1 = fp32
    else       flags[9] = (part[0] == 0) ? 1 : 0;   // 1 = int64 spk
  }
}

// ---------- adjacency from RAW inputs (identical values to canonical) ----------
__device__ __forceinline__ float adjr(int i, int j, int si, float m0, float m1, float m2,
                                      const void* __restrict__ spk,
                                      const void* __restrict__ mk, int fm, int fs) {
  if (i == j) return 1.0f;
  float t = expf(-0.1f * fabsf((float)(i - j)));
  if (ldspk(spk, j, fs) == si) return 0.8f * t;
  float ms = fabsf(m0 - ldx(mk, (long)j * 3, fm)) +
             fabsf(m1 - ldx(mk, (long)j * 3 + 1, fm)) +
             fabsf(m2 - ldx(mk, (long)j * 3 + 2, fm));
  return 0.5f * t * (1.0f - ms * (1.0f / 3.0f));
}

// ---------- canonicalize + prep2 + band rows (one full-occupancy kernel) ----------
#define FEATBLK 3712   // 4096*1856 / 8 / 256
#define NWBLK 1120     // (237568 + 32768 + 16384) / 256
__global__ __launch_bounds__(256) void prep(
    const void* feat, const void* Wp, const void* W1, const void* W2,
    const void* masks, const void* spk,
    const void* x0, const void* x1, const void* x2,
    const int* __restrict__ flags,
    u16* featc, u16* WpT, u16* W1T, u16* W2T,
    float* bp_c, float* b1c, float* b2c, u16* __restrict__ band) {
  __shared__ float part[256];
  __shared__ float invs;
  __shared__ float mxs[3][64];
  __shared__ int ord[3];
  const int blk = blockIdx.x, t = threadIdx.x;
  if (blk < FEATBLK) {
    if (!flags[0]) return;            // bf16 input: fused h0 reads feat directly
    long e = ((long)blk * 256 + t) * 8;
    const float* pf = (const float*)feat + e;
    u16 r[8];
    #pragma unroll
    for (int k = 0; k < 8; k++) r[k] = f2bf(pf[k]);
    *(bf16x8v*)(featc + e) = *(bf16x8v*)r;
    return;
  }
  if (blk < FEATBLK + NWBLK) {        // ---- weight transposes ----
    long e = (long)(blk - FEATBLK) * 256 + t;
    const int nWp = DIN * HN, nW1 = 2 * HN * HN;
    if (e < nWp) {  // e = input index k*HN+o; coalesced read, strided write
      int k = e >> 7, o = e & 127;
      WpT[(long)o * DIN + k] = f2bf(ldx(Wp, e, flags[2]));
      return;
    }
    e -= nWp;
    if (e < nW1) { int k = e >> 7, o = e & 127; W1T[(long)o * 256 + k] = f2bf(ldx(W1, e, flags[4])); return; }
    e -= nW1;
    { int k = e >> 7, o = e & 127; W2T[(long)o * 128 + k] = f2bf(ldx(W2, e, flags[6])); }
    return;
  }
  if (blk == FEATBLK + NWBLK) {       // ---- prep2 body ----
    const void* bs[3] = {x0, x1, x2};
    const int fl[3] = {flags[3], flags[5], flags[7]};
    if (t < 192) {
      int a = t / 64, e = t % 64;
      mxs[a][e] = fmaxf(fabsf(ldx(bs[a], e, fl[a])), fabsf(ldx(bs[a], e + 64, fl[a])));
    }
    __syncthreads();
    if (t == 0) {
      float mx[3];
      for (int a = 0; a < 3; a++) {
        float m = 0.f;
        for (int e = 0; e < 64; e++) m = fmaxf(m, mxs[a][e]);
        mx[a] = m;
      }
      int imin = 0, imax = 0;
      for (int k = 1; k < 3; k++) { if (mx[k] < mx[imin]) imin = k; if (mx[k] > mx[imax]) imax = k; }
      int imid = 3 - imin - imax;
      if (imin == imax) { imin = 0; imid = 1; imax = 2; }
      ord[0] = imin; ord[1] = imid; ord[2] = imax;
    }
    __syncthreads();
    if (t < HN) {
      bp_c[t] = ldx(bs[ord[0]], t, fl[ord[0]]);
      b1c[t]  = ldx(bs[ord[1]], t, fl[ord[1]]);
      b2c[t]  = ldx(bs[ord[2]], t, fl[ord[2]]);
    }
    return;
  }
  // ---- band row (bit-identical to build_band; raw-input reads) ----
  {
    const int i = blk - FEATBLK - NWBLK - 1;
    const int fm = flags[1], fs = flags[9];
    const int si = ldspk(spk, i, fs);
    const float m0 = ldx(masks, (long)i * 3, fm);
    const float m1 = ldx(masks, (long)i * 3 + 1, fm);
    const float m2 = ldx(masks, (long)i * 3 + 2, fm);
    float s = 0.f;
    for (int j = t; j < BN; j += 256) s += adjr(i, j, si, m0, m1, m2, spk, masks, fm, fs);
    part[t] = s;
    __syncthreads();
    if (t == 0) {
      float tot = 0.f;
      for (int k = 0; k < 256; k++) tot += part[k];   // serial: original order
      invs = 1.0f / (tot + 1e-8f);
    }
    __syncthreads();
    const float inv = invs;
    const int jbase = (i & ~15) - 128;
    for (int k = t; k < TILEW; k += 256) {
      int j = jbase + k;
      float v = 0.f;
      if (j >= 0 && j < BN) v = adjr(i, j, si, m0, m1, m2, spk, masks, fm, fs) * inv;
      band[(long)i * TILEW + k] = f2bf(v);
    }
  }
}

// snapshot buffer geometry (u16 units): [4096 guard][HN*BN data][4096 guard]
#define SNAP_ELEMS ((size_t)HN * BN + 8192)

// ---------- fused h0 + 16 RK4 stages: ONE WAVE PER TILE, no barriers ----------
// Snapshot k in its own single-write buffer: h0 -> snap 0; stage s -> snap s+1.
// Stage s reads snap s from tiles tile-8..tile+11. Producer adds +1 to padded
// inboxes of consumers [tile-11, tile+8] per publish (after own vmcnt drain).
// Consumer lane 0 polls inbox >= nprod*(s+1); wave reconverges; no barriers.
__global__ __launch_bounds__(64, 1) void fused_ode(
    const void* __restrict__ feat, const int* __restrict__ flags,
    const u16* __restrict__ featc, const u16* __restrict__ WpT,
    const float* __restrict__ bp_c, const u16* __restrict__ band,
    const u16* __restrict__ W1T, const u16* __restrict__ W2T,
    const float* __restrict__ b1c, const float* __restrict__ b2c,
    u16* __restrict__ hsb, float* __restrict__ outp,
    int* __restrict__ inbox) {
  __shared__ u16 w1l[128 * 264];     // W1T staged, padded stride (2-way bank)
  __shared__ u16 w2l[128 * 136];     // W2T staged, padded stride
  __shared__ u16 hc[16][264];        // [hs(0:128) | agg(128:256)] i-major
  __shared__ u16 zt[16][136];        // tanh output i-major

  const int lane = threadIdx.x;
  const int m = lane & 15, q = lane >> 4;
  // XCD swizzle: XCD x (blocks b%8==x round-robin) hosts contiguous tiles
  // [32x, 32x+31] -> window reads L2-resident (perf only; placement-agnostic).
  const int blk = blockIdx.x;
  const int tile = ((blk & 7) << 5) | (blk >> 3);
  const int r0 = tile * 16, jb = r0 - 128;
  const int i0 = r0 + q * 4;

  const int plo = (tile - 8 < 0) ? 0 : tile - 8;
  const int phi = (tile + 11 > 255) ? 255 : tile + 11;
  const int nprod = phi - plo + 1;
  const int cons = tile - 11 + lane;
  const int cvalid = (lane < 20) && (cons >= 0) && (cons < 256);

  // ---- stage weights into LDS (FIXED: 8-u16 chunks, full coverage) ----
  for (int idx = lane; idx < 128 * 32; idx += 64) {   // W1: 256 u16/row = 32 chunks
    int row = idx >> 5, seg = (idx & 31) * 8;
    *(bf16x8v*)&w1l[row * 264 + seg] = *(const bf16x8v*)(W1T + (long)row * 256 + seg);
  }
  for (int idx = lane; idx < 128 * 16; idx += 64) {   // W2: 128 u16/row = 16 chunks
    int row = idx >> 4, seg = (idx & 15) * 8;
    *(bf16x8v*)&w2l[row * 136 + seg] = *(const bf16x8v*)(W2T + (long)row * 128 + seg);
  }

  // ---- persistent band fragments + biases ----
  const f32x4 zero4 = {0.f, 0.f, 0.f, 0.f};
  bf16x8v bnd[10];
  {
    const u16* bandrow = band + (long)tile * 5120 + m * TILEW;
    #pragma unroll
    for (int kf = 0; kf < 10; kf++) {
      int k = (kf >> 1) * 64 + (kf & 1) * 32 + q * 8;
      bnd[kf] = *(const bf16x8v*)(bandrow + k);
    }
  }
  float b1v[8], b2v[8];
  #pragma unroll
  for (int nt = 0; nt < 8; nt++) { b1v[nt] = b1c[nt * 16 + m]; b2v[nt] = b2c[nt * 16 + m]; }

  // ---- h0 = feat @ Wp + bp: 8 chains, kf-ascending per chain (bit-identical) ----
  f32x4 hb[8];
  {
    f32x4 a0[8];
    #pragma unroll
    for (int nt = 0; nt < 8; nt++) a0[nt] = zero4;
    const u16* fbase = flags[0] ? featc : (const u16*)feat;
    const u16* arow = fbase + (long)(r0 + m) * DIN;
    #pragma unroll 2
    for (int kf = 0; kf < 58; kf++) {   // 58 * 32 = 1856
      int k = (kf >> 1) * 64 + (kf & 1) * 32 + q * 8;
      bf16x8v a = *(const bf16x8v*)(arow + k);
      #pragma unroll
      for (int nt = 0; nt < 8; nt++) {
        bf16x8v b = *(const bf16x8v*)(WpT + (long)(nt * 16 + m) * DIN + k);
        a0[nt] = MFMA16(a, b, a0[nt]);
      }
    }
    #pragma unroll
    for (int nt = 0; nt < 8; nt++) { a0[nt] += bp_c[nt * 16 + m]; hb[nt] = a0[nt]; }
  }
  f32x4 acr[8];
  #pragma unroll
  for (int nt = 0; nt < 8; nt++) acr[nt] = zero4;
  {
    u16* snap0 = hsb + 4096;
    #pragma unroll
    for (int nt = 0; nt < 8; nt++) {
      const int n0 = nt * 16 + m;
      ushort4 hsv;
      hsv.x = f2bf(hb[nt][0]); hsv.y = f2bf(hb[nt][1]);
      hsv.z = f2bf(hb[nt][2]); hsv.w = f2bf(hb[nt][3]);
      union { ushort4 s4; u64 q8; } pu; pu.s4 = hsv;
      cstore8(&snap0[(long)n0 * BN + i0], pu.q8);
      hc[q * 4 + 0][n0] = hsv.x; hc[q * 4 + 1][n0] = hsv.y;
      hc[q * 4 + 2][n0] = hsv.z; hc[q * 4 + 3][n0] = hsv.w;
    }
  }
  asm volatile("s_waitcnt vmcnt(0)" ::: "memory");     // own publish at LLC
  if (cvalid)
    __hip_atomic_fetch_add(&inbox[cons * IBSTRIDE], 1, __ATOMIC_RELAXED,
                           __HIP_MEMORY_SCOPE_AGENT);

  const float dt6 = 0.25f / 6.0f;

  #pragma unroll 1
  for (int s = 0; s < 16; s++) {
    const int sub = s & 3;

    // ---- lane-0 poll; wave reconverges (no barrier) ----
    if (lane == 0) {
      const int tgt = nprod * (s + 1);
      while (__hip_atomic_load(&inbox[tile * IBSTRIDE], __ATOMIC_RELAXED,
                               __HIP_MEMORY_SCOPE_AGENT) < tgt)
        __builtin_amdgcn_s_sleep(1);
    }
    asm volatile("" ::: "memory");   // keep window loads below the spin

    // phase 1: banded agg — A from band regs, B via plain cached loads
    f32x4 g[8];
    #pragma unroll
    for (int nt = 0; nt < 8; nt++) g[nt] = zero4;
    const u16* snapr = hsb + (size_t)s * SNAP_ELEMS + 4096 + jb;
    #pragma unroll
    for (int kf = 0; kf < 10; kf++) {
      int k = (kf >> 1) * 64 + (kf & 1) * 32 + q * 8;
      #pragma unroll
      for (int nt = 0; nt < 8; nt++) {
        bf16x8v b = *(const bf16x8v*)(snapr + (long)(nt * 16 + m) * BN + k);
        g[nt] = MFMA16(bnd[kf], b, g[nt]);
      }
    }
    #pragma unroll
    for (int nt = 0; nt < 8; nt++) {
      const int n0 = nt * 16 + m;
      #pragma unroll
      for (int r = 0; r < 4; r++) hc[q * 4 + r][128 + n0] = f2bf(g[nt][r]);
    }

    // GEMM1: z = hc @ W1 — A from LDS (in-wave lgkmcnt orders vs writes)
    f32x4 z[8];
    #pragma unroll
    for (int nt = 0; nt < 8; nt++) z[nt] = zero4;
    #pragma unroll
    for (int kf = 0; kf < 8; kf++) {
      int k = (kf >> 1) * 64 + (kf & 1) * 32 + q * 8;
      bf16x8v a = *(const bf16x8v*)&hc[m][k];
      #pragma unroll
      for (int nt = 0; nt < 8; nt++) {
        bf16x8v b = *(const bf16x8v*)&w1l[(nt * 16 + m) * 264 + k];
        z[nt] = MFMA16(a, b, z[nt]);
      }
    }
    #pragma unroll
    for (int nt = 0; nt < 8; nt++) {
      const int n0 = nt * 16 + m;
      #pragma unroll
      for (int r = 0; r < 4; r++) zt[q * 4 + r][n0] = f2bf(tanhf(z[nt][r] + b1v[nt]));
    }

    // GEMM2: k = z @ W2
    f32x4 kk[8];
    #pragma unroll
    for (int nt = 0; nt < 8; nt++) kk[nt] = zero4;
    #pragma unroll
    for (int kf = 0; kf < 4; kf++) {
      int k = (kf >> 1) * 64 + (kf & 1) * 32 + q * 8;
      bf16x8v a = *(const bf16x8v*)&zt[m][k];
      #pragma unroll
      for (int nt = 0; nt < 8; nt++) {
        bf16x8v b = *(const bf16x8v*)&w2l[(nt * 16 + m) * 136 + k];
        kk[nt] = MFMA16(a, b, kk[nt]);
      }
    }

    // RK4 update + publish — identical fp32 expression order to round 9
    u16* snapw = hsb + (size_t)(s + 1) * SNAP_ELEMS + 4096;
    #pragma unroll
    for (int nt = 0; nt < 8; nt++) {
      f32x4 kv = kk[nt];
      kv += b2v[nt];
      f32x4 hn;
      if (sub == 0)      { acr[nt] = 1.f * kv;  hn = hb[nt] + 0.125f * kv; }
      else if (sub == 1) { acr[nt] += 2.f * kv; hn = hb[nt] + 0.125f * kv; }
      else if (sub == 2) { acr[nt] += 2.f * kv; hn = hb[nt] + 0.25f  * kv; }
      else {
        hn = hb[nt] + dt6 * (acr[nt] + kv);
        hb[nt] = hn;
        if (s == 15) {
          #pragma unroll
          for (int r = 0; r < 4; r++)
            outp[(long)(i0 + r) * HN + nt * 16 + m] = hn[r];  // fp32
        }
      }
      if (s < 15) {
        const int n0 = nt * 16 + m;
        ushort4 hsv;
        hsv.x = f2bf(hn[0]); hsv.y = f2bf(hn[1]); hsv.z = f2bf(hn[2]); hsv.w = f2bf(hn[3]);
        union { ushort4 s4; u64 q8; } pu; pu.s4 = hsv;
        cstore8(&snapw[(long)n0 * BN + i0], pu.q8);
        hc[q * 4 + 0][n0] = hsv.x; hc[q * 4 + 1][n0] = hsv.y;
        hc[q * 4 + 2][n0] = hsv.z; hc[q * 4 + 3][n0] = hsv.w;
      }
    }
    if (s < 15) {
      asm volatile("s_waitcnt vmcnt(0)" ::: "memory");   // own publish at LLC
      if (cvalid)
        __hip_atomic_fetch_add(&inbox[cons * IBSTRIDE], 1, __ATOMIC_RELAXED,
                               __HIP_MEMORY_SCOPE_AGENT);
    }
  }
}

// ---------- launch ----------
extern "C" void kernel_launch(void* const* d_in, const int* in_sizes, int n_in,
                              void* d_out, int out_size, void* d_ws, size_t ws_size,
                              hipStream_t stream) {
  const void* feat = nullptr; const void* spk = nullptr; const void* masks = nullptr;
  const void* Wp = nullptr; const void* W1 = nullptr; const void* W2 = nullptr;
  const void* bias[3] = {nullptr, nullptr, nullptr};
  int nb = 0;
  for (int k = 0; k < n_in; k++) {
    switch (in_sizes[k]) {
      case BN * DIN:    feat = d_in[k]; break;
      case BN:          spk = d_in[k]; break;
      case BN * 3:      masks = d_in[k]; break;
      case DIN * HN:    Wp = d_in[k]; break;
      case 2 * HN * HN: W1 = d_in[k]; break;
      case HN * HN:     W2 = d_in[k]; break;
      default:          if (in_sizes[k] == HN && nb < 3) bias[nb++] = d_in[k]; break;
    }
  }
  float* out = (float*)d_out;

  char* p = (char*)d_ws;
  int*   flags   = (int*)p;   p += 64;
  float* bp_c    = (float*)p; p += 512;
  float* b1c     = (float*)p; p += 512;
  float* b2c     = (float*)p; p += 512;
  int*   inbox   = (int*)p;   p += 256 * IBSTRIDE * 4;      // 256 padded counters (32KB)
  u16*   featc   = (u16*)p;   p += (size_t)BN * DIN * 2;    // 15,204,352
  u16*   WpT     = (u16*)p;   p += (size_t)HN * DIN * 2;
  u16*   W1T     = (u16*)p;   p += (size_t)HN * 256 * 2;
  u16*   W2T     = (u16*)p;   p += (size_t)HN * HN * 2;
  u16*   band    = (u16*)p;   p += (size_t)BN * TILEW * 2;
  u16*   hsb     = (u16*)p;   p += 16 * SNAP_ELEMS * 2;     // 16 snapshots ~17 MB
  (void)ws_size; (void)out_size;                            // total ~36 MB

  detect<<<10, 256, 0, stream>>>(feat, masks, Wp, bias[0], W1, bias[1], W2, bias[2],
                                 (const unsigned*)spk, flags, inbox);
  prep<<<FEATBLK + NWBLK + 1 + BN, 256, 0, stream>>>(
      feat, Wp, W1, W2, masks, spk, bias[0], bias[1], bias[2], flags,
      featc, WpT, W1T, W2T, bp_c, b1c, b2c, band);

  // 256 blocks x 64 thr: one wave per tile, 1 block/CU (115KB LDS), all
  // resident at dispatch -> flag-spin deadlock-free.
  fused_ode<<<dim3(256), dim3(64), 0, stream>>>(
      feat, flags, featc, WpT, bp_c, band, W1T, W2T, b1c, b2c,
      hsb, out, inbox);
}

// Round 21
// 225.844 us; speedup vs baseline: 1.7295x; 1.7295x over previous
//
#include <hip/hip_runtime.h>

// DGODE — round 22: REVERT to round-19 (best measured: 225.2us total,
//   fused_ode 110us, absmax 0.015625).
//   r20/21 one-wave experiment measured 276us fused: 1 wave/CU = no TLP,
//   8x serial per-wave work on one SIMD >> the ~3us/stage barrier cost it
//   removed. Both structural directions now measured (more waves: r13/r16
//   regressed; fewer waves: r20/21 regressed) -> the 8-wave x 16-row tile
//   with padded-mailbox push sync is the optimum for this decomposition.
//   This source is byte-identical in structure to the round-19 kernel that
//   measured 225.2us in round 17.
// Same MFMA sequence per (m,n,k), same fp32 expression order => bit-identical
// output (absmax 0.015625).

typedef unsigned short u16;
typedef unsigned long long u64;
typedef __attribute__((ext_vector_type(8))) short bf16x8v;
typedef __attribute__((ext_vector_type(4))) float f32x4;

#define MFMA16(a, b, c) __builtin_amdgcn_mfma_f32_16x16x32_bf16(a, b, c, 0, 0, 0)

#define BN 4096
#define HN 128
#define DIN 1856
#define TILEW 320
#define IBSTRIDE 32   // inbox counter stride in ints (128B) — one LLC line each

__device__ __forceinline__ float bf2f(u16 u) {
  union { unsigned u; float f; } v; v.u = ((unsigned)u) << 16; return v.f;
}
__device__ __forceinline__ u16 f2bf(float f) {
  union { float f; unsigned u; } v; v.f = f;
  unsigned u = v.u;
  return (u16)((u + 0x7fffu + ((u >> 16) & 1u)) >> 16);  // RNE
}
__device__ __forceinline__ float ldx(const void* p, long idx, int isf) {
  return isf ? ((const float*)p)[idx] : bf2f(((const u16*)p)[idx]);
}
__device__ __forceinline__ int ldspk(const void* spk, int j, int i64) {
  return i64 ? ((const int*)spk)[2 * j] : ((const int*)spk)[j];
}

// coherent (LLC-point) 8B store, no cache maintenance (producer publish path)
__device__ __forceinline__ void cstore8(u16* p, u64 v) {
  __hip_atomic_store((u64*)p, v, __ATOMIC_RELAXED, __HIP_MEMORY_SCOPE_AGENT);
}

// ---------- per-array dtype detection (parallel) + inbox zeroing ----------
__global__ __launch_bounds__(256) void detect(
    const void* a0, const void* a1, const void* a2, const void* a3,
    const void* a4, const void* a5, const void* a6, const void* a7,
    const unsigned* spk_raw, int* flags, int* inbox) {
  __shared__ int part[256];
  const int b = blockIdx.x, t = threadIdx.x;
  int cnt = 0;
  if (b < 8) {
    const void* arr[8] = {a0, a1, a2, a3, a4, a5, a6, a7};
    const int nel[8] = {BN * DIN, BN * 3, DIN * HN, HN, 2 * HN * HN, HN, HN * HN, HN};
    const u16* p = (const u16*)arr[b];
    int ns = nel[b] / 2; if (ns > 512) ns = 512;
    for (int e = t; e < ns; e += 256) {
      unsigned ex = (p[2 * e] >> 7) & 0xFFu;
      if (ex < 64u) cnt++;
    }
  } else if (b == 8) {
    for (int e = t; e < 512; e += 256)
      if (spk_raw[2 * e + 1] != 0u) cnt++;
  } else {
    inbox[t * IBSTRIDE] = 0;   // b == 9: zero 256 padded inbox counters
    return;
  }
  part[t] = cnt;
  __syncthreads();
  #pragma unroll
  for (int o = 128; o > 0; o >>= 1) {
    if (t < o) part[t] += part[t + o];
    __syncthreads();
  }
  if (t == 0) {
    if (b < 8) flags[b] = (part[0] >= 2) ? 1 : 0;   // 1 = fp32
    else       flags[9] = (part[0] == 0) ? 1 : 0;   // 1 = int64 spk
  }
}

// ---------- adjacency from RAW inputs (identical values to canonical) ----------
__device__ __forceinline__ float adjr(int i, int j, int si, float m0, float m1, float m2,
                                      const void* __restrict__ spk,
                                      const void* __restrict__ mk, int fm, int fs) {
  if (i == j) return 1.0f;
  float t = expf(-0.1f * fabsf((float)(i - j)));
  if (ldspk(spk, j, fs) == si) return 0.8f * t;
  float ms = fabsf(m0 - ldx(mk, (long)j * 3, fm)) +
             fabsf(m1 - ldx(mk, (long)j * 3 + 1, fm)) +
             fabsf(m2 - ldx(mk, (long)j * 3 + 2, fm));
  return 0.5f * t * (1.0f - ms * (1.0f / 3.0f));
}

// ---------- canonicalize + prep2 + band rows (one full-occupancy kernel) ----------
#define FEATBLK 3712   // 4096*1856 / 8 / 256
#define NWBLK 1120     // (237568 + 32768 + 16384) / 256
__global__ __launch_bounds__(256) void prep(
    const void* feat, const void* Wp, const void* W1, const void* W2,
    const void* masks, const void* spk,
    const void* x0, const void* x1, const void* x2,
    const int* __restrict__ flags,
    u16* featc, u16* WpT, u16* W1T, u16* W2T,
    float* bp_c, float* b1c, float* b2c, u16* __restrict__ band) {
  __shared__ float part[256];
  __shared__ float invs;
  __shared__ float mxs[3][64];
  __shared__ int ord[3];
  const int blk = blockIdx.x, t = threadIdx.x;
  if (blk < FEATBLK) {
    if (!flags[0]) return;            // bf16 input: fused h0 reads feat directly
    long e = ((long)blk * 256 + t) * 8;
    const float* pf = (const float*)feat + e;
    u16 r[8];
    #pragma unroll
    for (int k = 0; k < 8; k++) r[k] = f2bf(pf[k]);
    *(bf16x8v*)(featc + e) = *(bf16x8v*)r;
    return;
  }
  if (blk < FEATBLK + NWBLK) {        // ---- weight transposes ----
    long e = (long)(blk - FEATBLK) * 256 + t;
    const int nWp = DIN * HN, nW1 = 2 * HN * HN;
    if (e < nWp) {  // e = input index k*HN+o; coalesced read, strided write
      int k = e >> 7, o = e & 127;
      WpT[(long)o * DIN + k] = f2bf(ldx(Wp, e, flags[2]));
      return;
    }
    e -= nWp;
    if (e < nW1) { int k = e >> 7, o = e & 127; W1T[(long)o * 256 + k] = f2bf(ldx(W1, e, flags[4])); return; }
    e -= nW1;
    { int k = e >> 7, o = e & 127; W2T[(long)o * 128 + k] = f2bf(ldx(W2, e, flags[6])); }
    return;
  }
  if (blk == FEATBLK + NWBLK) {       // ---- prep2 body ----
    const void* bs[3] = {x0, x1, x2};
    const int fl[3] = {flags[3], flags[5], flags[7]};
    if (t < 192) {
      int a = t / 64, e = t % 64;
      mxs[a][e] = fmaxf(fabsf(ldx(bs[a], e, fl[a])), fabsf(ldx(bs[a], e + 64, fl[a])));
    }
    __syncthreads();
    if (t == 0) {
      float mx[3];
      for (int a = 0; a < 3; a++) {
        float m = 0.f;
        for (int e = 0; e < 64; e++) m = fmaxf(m, mxs[a][e]);
        mx[a] = m;
      }
      int imin = 0, imax = 0;
      for (int k = 1; k < 3; k++) { if (mx[k] < mx[imin]) imin = k; if (mx[k] > mx[imax]) imax = k; }
      int imid = 3 - imin - imax;
      if (imin == imax) { imin = 0; imid = 1; imax = 2; }
      ord[0] = imin; ord[1] = imid; ord[2] = imax;
    }
    __syncthreads();
    if (t < HN) {
      bp_c[t] = ldx(bs[ord[0]], t, fl[ord[0]]);
      b1c[t]  = ldx(bs[ord[1]], t, fl[ord[1]]);
      b2c[t]  = ldx(bs[ord[2]], t, fl[ord[2]]);
    }
    return;
  }
  // ---- band row (bit-identical to build_band; raw-input reads) ----
  {
    const int i = blk - FEATBLK - NWBLK - 1;
    const int fm = flags[1], fs = flags[9];
    const int si = ldspk(spk, i, fs);
    const float m0 = ldx(masks, (long)i * 3, fm);
    const float m1 = ldx(masks, (long)i * 3 + 1, fm);
    const float m2 = ldx(masks, (long)i * 3 + 2, fm);
    float s = 0.f;
    for (int j = t; j < BN; j += 256) s += adjr(i, j, si, m0, m1, m2, spk, masks, fm, fs);
    part[t] = s;
    __syncthreads();
    if (t == 0) {
      float tot = 0.f;
      for (int k = 0; k < 256; k++) tot += part[k];   // serial: original order
      invs = 1.0f / (tot + 1e-8f);
    }
    __syncthreads();
    const float inv = invs;
    const int jbase = (i & ~15) - 128;
    for (int k = t; k < TILEW; k += 256) {
      int j = jbase + k;
      float v = 0.f;
      if (j >= 0 && j < BN) v = adjr(i, j, si, m0, m1, m2, spk, masks, fm, fs) * inv;
      band[(long)i * TILEW + k] = f2bf(v);
    }
  }
}

// snapshot buffer geometry (u16 units): [4096 guard][HN*BN data][4096 guard]
#define SNAP_ELEMS ((size_t)HN * BN + 8192)

// ---------- fused h0 + 16 RK4 stages (padded-mailbox push sync) ----------
// Snapshot k lives in its own single-write buffer: h0 -> snap 0; stage s
// output -> snap s+1. Stage s reads snap s from tiles tile-8..tile+11.
// Producer P pushes +1 to padded inboxes of consumers [P-11, P+8] per publish.
// Consumer T proceeds when inbox[T*IBSTRIDE] >= N_T*(s+1).
__global__ __launch_bounds__(512, 2) void fused_ode(
    const void* __restrict__ feat, const int* __restrict__ flags,
    const u16* __restrict__ featc, const u16* __restrict__ WpT,
    const float* __restrict__ bp_c, const u16* __restrict__ band,
    const u16* __restrict__ W1T, const u16* __restrict__ W2T,
    const float* __restrict__ b1c, const float* __restrict__ b2c,
    u16* __restrict__ hsb, float* __restrict__ outp,
    int* __restrict__ inbox) {
  __shared__ u16 hc[16][264];        // [hs(0:128) | agg(128:256)] i-major
  __shared__ u16 zt[16][136];        // tanh output i-major

  const int tid = threadIdx.x, w = tid >> 6, lane = tid & 63;
  const int m = lane & 15, q = lane >> 4;
  // XCD-aware tile swizzle (perf heuristic; correctness placement-independent)
  const int blk = blockIdx.x;
  const int tile = ((blk & 7) << 5) | (blk >> 3);
  const int r0 = tile * 16, jb = r0 - 128;
  const int n0 = w * 16 + m;
  const int i0 = r0 + q * 4;
  const long base = (long)n0 * BN + i0;

  // exact in-range producer count for this tile's window [tile-8, tile+11]
  const int plo = (tile - 8 < 0) ? 0 : tile - 8;
  const int phi = (tile + 11 > 255) ? 255 : tile + 11;
  const int nprod = phi - plo + 1;
  // this thread's consumer push target (tids 0..19): [tile-11, tile+8]
  const int cons = tile - 11 + tid;
  const int cvalid = (tid < 20) && (cons >= 0) && (cons < 256);

  // persistent operand registers (loaded once, reused all 16 stages)
  bf16x8v w1r[8], w2r[4], bnd[10];
  {
    const u16* w1row = W1T + (long)n0 * 256;
    #pragma unroll
    for (int kf = 0; kf < 8; kf++) {
      int k = (kf >> 1) * 64 + (kf & 1) * 32 + q * 8;
      w1r[kf] = *(const bf16x8v*)(w1row + k);
    }
    const u16* w2row = W2T + (long)n0 * 128;
    #pragma unroll
    for (int kf = 0; kf < 4; kf++) {
      int k = (kf >> 1) * 64 + (kf & 1) * 32 + q * 8;
      w2r[kf] = *(const bf16x8v*)(w2row + k);
    }
    const u16* bandrow = band + (long)tile * 5120 + m * TILEW;
    #pragma unroll
    for (int kf = 0; kf < 10; kf++) {
      int k = (kf >> 1) * 64 + (kf & 1) * 32 + q * 8;
      bnd[kf] = *(const bf16x8v*)(bandrow + k);
    }
  }
  const float b1v = b1c[n0], b2v = b2c[n0];

  // ---- h0 = feat @ Wp + bp (identical bits: featc when fp32, raw when bf16) ----
  f32x4 hb;
  {
    const u16* fbase = flags[0] ? featc : (const u16*)feat;
    f32x4 a0 = {0, 0, 0, 0};
    const u16* arow = fbase + (long)(r0 + m) * DIN;
    const u16* brow = WpT + (long)n0 * DIN;
    #pragma unroll 4
    for (int kf = 0; kf < 58; kf++) {   // 58 * 32 = 1856
      int k = (kf >> 1) * 64 + (kf & 1) * 32 + q * 8;
      bf16x8v a = *(const bf16x8v*)(arow + k);
      bf16x8v b = *(const bf16x8v*)(brow + k);
      a0 = MFMA16(a, b, a0);
    }
    a0 += bp_c[n0];
    hb = a0;
  }
  f32x4 acc = {0, 0, 0, 0};
  {
    u16* snap0 = hsb + 4096;                           // snapshot 0 data
    ushort4 hsv;
    hsv.x = f2bf(hb[0]); hsv.y = f2bf(hb[1]); hsv.z = f2bf(hb[2]); hsv.w = f2bf(hb[3]);
    union { ushort4 s; u64 q8; } pu; pu.s = hsv;
    cstore8(&snap0[base], pu.q8);                      // cross-block snapshot 0
    hc[q * 4 + 0][n0] = hsv.x; hc[q * 4 + 1][n0] = hsv.y;  // own-block, direct
    hc[q * 4 + 2][n0] = hsv.z; hc[q * 4 + 3][n0] = hsv.w;
  }
  asm volatile("s_waitcnt vmcnt(0)" ::: "memory");     // hs stores at LLC
  __syncthreads();
  if (cvalid)
    __hip_atomic_fetch_add(&inbox[cons * IBSTRIDE], 1, __ATOMIC_RELAXED,
                           __HIP_MEMORY_SCOPE_AGENT);

  const float dt6 = 0.25f / 6.0f;

  #pragma unroll 1
  for (int s = 0; s < 16; s++) {
    const int sub = s & 3;

    // GEMM1 own-hs half (kf 0..3) — no neighbor dependency; overlaps handoff
    f32x4 z0 = {0, 0, 0, 0};
    #pragma unroll
    for (int kf = 0; kf < 4; kf++) {
      int k = (kf >> 1) * 64 + (kf & 1) * 32 + q * 8;
      bf16x8v a = *(const bf16x8v*)&hc[m][k];
      z0 = MFMA16(a, w1r[kf], z0);
    }

    // ---- single-poller wait on private padded line ----
    if (tid == 0) {
      const int tgt = nprod * (s + 1);
      while (__hip_atomic_load(&inbox[tile * IBSTRIDE], __ATOMIC_RELAXED,
                               __HIP_MEMORY_SCOPE_AGENT) < tgt)
        __builtin_amdgcn_s_sleep(1);
    }
    __syncthreads();

    // phase 1: banded agg — A from band regs, B via plain cached loads
    // (snapshot buffer is single-write: no stale copy can exist).
    f32x4 g0 = {0, 0, 0, 0};
    const u16* hrow = hsb + (size_t)s * SNAP_ELEMS + 4096 + (long)n0 * BN + jb;
    #pragma unroll
    for (int kf = 0; kf < 10; kf++) {
      int k = (kf >> 1) * 64 + (kf & 1) * 32 + q * 8;
      bf16x8v b = *(const bf16x8v*)(hrow + k);
      g0 = MFMA16(bnd[kf], b, g0);
    }
    #pragma unroll
    for (int r = 0; r < 4; r++) hc[q * 4 + r][128 + n0] = f2bf(g0[r]);
    __syncthreads();

    // GEMM1 agg half (kf 4..7) — completes z0 in original accumulation order
    #pragma unroll
    for (int kf = 4; kf < 8; kf++) {
      int k = (kf >> 1) * 64 + (kf & 1) * 32 + q * 8;
      bf16x8v a = *(const bf16x8v*)&hc[m][k];
      z0 = MFMA16(a, w1r[kf], z0);
    }
    #pragma unroll
    for (int r = 0; r < 4; r++) zt[q * 4 + r][n0] = f2bf(tanhf(z0[r] + b1v));
    __syncthreads();

    // GEMM2: k = z @ W2 — A from LDS, B from persistent regs
    f32x4 k0 = {0, 0, 0, 0};
    #pragma unroll
    for (int kf = 0; kf < 4; kf++) {
      int k = (kf >> 1) * 64 + (kf & 1) * 32 + q * 8;
      bf16x8v a = *(const bf16x8v*)&zt[m][k];
      k0 = MFMA16(a, w2r[kf], k0);
    }
    f32x4 kv = k0;
    kv += b2v;

    // RK4 update — identical fp32 expression order to round 9
    f32x4 hn;
    if (sub == 0)      { acc = 1.f * kv;  hn = hb + 0.125f * kv; }
    else if (sub == 1) { acc += 2.f * kv; hn = hb + 0.125f * kv; }
    else if (sub == 2) { acc += 2.f * kv; hn = hb + 0.25f  * kv; }
    else {
      hn = hb + dt6 * (acc + kv);
      hb = hn;
      if (s == 15) {
        #pragma unroll
        for (int r = 0; r < 4; r++) outp[(long)(i0 + r) * HN + n0] = hn[r];  // fp32
      }
    }

    if (s < 15) {
      // publish snapshot s+1: LLC store (neighbors) + LDS left half (own)
      u16* snapw = hsb + (size_t)(s + 1) * SNAP_ELEMS + 4096;
      ushort4 hsv;
      hsv.x = f2bf(hn[0]); hsv.y = f2bf(hn[1]); hsv.z = f2bf(hn[2]); hsv.w = f2bf(hn[3]);
      union { ushort4 s4; u64 q8; } pu; pu.s4 = hsv;
      cstore8(&snapw[base], pu.q8);
      hc[q * 4 + 0][n0] = hsv.x; hc[q * 4 + 1][n0] = hsv.y;
      hc[q * 4 + 2][n0] = hsv.z; hc[q * 4 + 3][n0] = hsv.w;
      asm volatile("s_waitcnt vmcnt(0)" ::: "memory");   // hs stores at LLC
      __syncthreads();
      if (cvalid)
        __hip_atomic_fetch_add(&inbox[cons * IBSTRIDE], 1, __ATOMIC_RELAXED,
                               __HIP_MEMORY_SCOPE_AGENT);
    }
  }
}

// ---------- launch ----------
extern "C" void kernel_launch(void* const* d_in, const int* in_sizes, int n_in,
                              void* d_out, int out_size, void* d_ws, size_t ws_size,
                              hipStream_t stream) {
  const void* feat = nullptr; const void* spk = nullptr; const void* masks = nullptr;
  const void* Wp = nullptr; const void* W1 = nullptr; const void* W2 = nullptr;
  const void* bias[3] = {nullptr, nullptr, nullptr};
  int nb = 0;
  for (int k = 0; k < n_in; k++) {
    switch (in_sizes[k]) {
      case BN * DIN:    feat = d_in[k]; break;
      case BN:          spk = d_in[k]; break;
      case BN * 3:      masks = d_in[k]; break;
      case DIN * HN:    Wp = d_in[k]; break;
      case 2 * HN * HN: W1 = d_in[k]; break;
      case HN * HN:     W2 = d_in[k]; break;
      default:          if (in_sizes[k] == HN && nb < 3) bias[nb++] = d_in[k]; break;
    }
  }
  float* out = (float*)d_out;

  char* p = (char*)d_ws;
  int*   flags   = (int*)p;   p += 64;
  float* bp_c    = (float*)p; p += 512;
  float* b1c     = (float*)p; p += 512;
  float* b2c     = (float*)p; p += 512;
  int*   inbox   = (int*)p;   p += 256 * IBSTRIDE * 4;      // 256 padded counters (32KB)
  u16*   featc   = (u16*)p;   p += (size_t)BN * DIN * 2;    // 15,204,352
  u16*   WpT     = (u16*)p;   p += (size_t)HN * DIN * 2;
  u16*   W1T     = (u16*)p;   p += (size_t)HN * 256 * 2;
  u16*   W2T     = (u16*)p;   p += (size_t)HN * HN * 2;
  u16*   band    = (u16*)p;   p += (size_t)BN * TILEW * 2;
  u16*   hsb     = (u16*)p;   p += 16 * SNAP_ELEMS * 2;     // 16 snapshots ~17 MB
  (void)ws_size; (void)out_size;                            // total ~36 MB

  detect<<<10, 256, 0, stream>>>(feat, masks, Wp, bias[0], W1, bias[1], W2, bias[2],
                                 (const unsigned*)spk, flags, inbox);
  prep<<<FEATBLK + NWBLK + 1 + BN, 256, 0, stream>>>(
      feat, Wp, W1, W2, masks, spk, bias[0], bias[1], bias[2], flags,
      featc, WpT, W1T, W2T, bp_c, b1c, b2c, band);

  // Regular launch: 256 blocks on 256 CUs (1 block/CU by resource fit) —
  // co-residency without the cooperative-launch overhead.
  fused_ode<<<dim3(BN / 16), dim3(512), 0, stream>>>(
      feat, flags, featc, WpT, bp_c, band, W1T, W2T, b1c, b2c,
      hsb, out, inbox);
}